// Round 8
// baseline (223.145 us; speedup 1.0000x reference)
//
#include <hip/hip_runtime.h>
#include <hip/hip_bf16.h>
#include <math.h>

#define B_  2
#define T_  2048
#define C_  1024
#define NH  16
#define HD  64

typedef __attribute__((ext_vector_type(8)))  short short8;
typedef __attribute__((ext_vector_type(4)))  float f32x4;
typedef __attribute__((ext_vector_type(16))) float f32x16;

__device__ __forceinline__ void gload_lds16(const void* g, void* l) {
    __builtin_amdgcn_global_load_lds(
        (const __attribute__((address_space(1))) void*)g,
        (__attribute__((address_space(3))) void*)l, 16, 0, 0);
}

__device__ __forceinline__ unsigned short f2bf(float f) {
    __hip_bfloat16 b = __float2bfloat16(f);
    return *reinterpret_cast<unsigned short*>(&b);
}
// fast round-half-up bf16 (valid for finite values; no NaN handling needed)
__device__ __forceinline__ unsigned short f2bf_fast(float f) {
    return (unsigned short)((__float_as_uint(f) + 0x8000u) >> 16);
}

// ---------------------------------------------------------------------------
// cast fp32 -> bf16, elementwise (4 per thread)
// ---------------------------------------------------------------------------
__global__ __launch_bounds__(256) void cast_bf16_kernel(
    const float* __restrict__ in, __hip_bfloat16* __restrict__ out, int n4)
{
    const int i = blockIdx.x * 256 + threadIdx.x;
    if (i >= n4) return;
    const float4 v = reinterpret_cast<const float4*>(in)[i];
    ushort4 o;
    o.x = f2bf(v.x); o.y = f2bf(v.y); o.z = f2bf(v.z); o.w = f2bf(v.w);
    reinterpret_cast<ushort4*>(out)[i] = o;
}

// ---------------------------------------------------------------------------
// transpose + cast: W[R][Ccols] fp32 -> Wt[Ccols][R] bf16
// ---------------------------------------------------------------------------
__global__ __launch_bounds__(256) void transpose_cast_kernel(
    const float* __restrict__ W, __hip_bfloat16* __restrict__ Wt, int R, int Ccols)
{
    __shared__ float tile[32][33];
    const int c0 = blockIdx.x * 32, r0 = blockIdx.y * 32;
    const int tx = threadIdx.x & 31, ty = threadIdx.x >> 5;  // ty 0..7
    #pragma unroll
    for (int i = 0; i < 32; i += 8)
        tile[ty + i][tx] = W[(size_t)(r0 + ty + i) * Ccols + c0 + tx];
    __syncthreads();
    #pragma unroll
    for (int i = 0; i < 32; i += 8)
        Wt[(size_t)(c0 + ty + i) * R + r0 + tx] = __float2bfloat16(tile[tx][ty + i]);
}

// ---------------------------------------------------------------------------
// 256x256 phase-interleaved bf16 MFMA GEMM (unchanged from round 7).
// ---------------------------------------------------------------------------
#define QBM 256
#define QBN 256
#define QBK 32

__global__ __launch_bounds__(512) void gemm_bf16_8ph(
    const __hip_bfloat16* __restrict__ A,   // [M,K]
    const __hip_bfloat16* __restrict__ Bt,  // [N,K]
    const float* __restrict__ bias,
    __hip_bfloat16* __restrict__ Cb,        // bf16 out
    __hip_bfloat16* __restrict__ vt,        // V^T side output (or null)
    int M, int N, int K, int gx)
{
    __shared__ __align__(16) __hip_bfloat16 As[4][QBM * QBK];  // 64 KB
    __shared__ __align__(16) __hip_bfloat16 Bs[4][QBN * QBK];  // 64 KB

    const int nwg = (int)gridDim.x;
    const int orig = (int)blockIdx.x;
    const int qq = nwg >> 3, rr = nwg & 7;
    const int xcd = orig & 7, off = orig >> 3;
    const int wgid = (xcd < rr ? xcd * (qq + 1)
                               : rr * (qq + 1) + (xcd - rr) * qq) + off;
    const int bx = wgid % gx;
    const int by = wgid / gx;

    const int tid = threadIdx.x;
    const int w = tid >> 6, lane = tid & 63;
    const int wm = w >> 2, wn = w & 3;          // 2 x 4 wave grid
    const int lr = lane & 15, kb = lane >> 4;   // row-in-frag / k-block

    const size_t rowA0 = (size_t)by * QBM;
    const size_t colB0 = (size_t)bx * QBN;

    const int rS   = tid >> 2;                  // 0..127  (+128 for g=1)
    const int blkl = tid & 3;
    const int bsw  = blkl ^ ((rS >> 1) & 3);
    const __hip_bfloat16* gA0 = A  + (rowA0 + rS) * K + bsw * 8;
    const __hip_bfloat16* gA1 = gA0 + (size_t)128 * K;
    const __hip_bfloat16* gB0 = Bt + (colB0 + rS) * K + bsw * 8;
    const __hip_bfloat16* gB1 = gB0 + (size_t)128 * K;

    const int NT = K / QBK;   // 32

    #define STAGE_A(t) { char* d = (char*)As[(t) & 3] + tid * 16;            \
        gload_lds16(gA0 + (t) * QBK, d);                                     \
        gload_lds16(gA1 + (t) * QBK, d + 8192); }
    #define STAGE_B(t) { char* d = (char*)Bs[(t) & 3] + tid * 16;            \
        gload_lds16(gB0 + (t) * QBK, d);                                     \
        gload_lds16(gB1 + (t) * QBK, d + 8192); }

    const int rowAl = wm * 128 + lr;
    const int rowBl = wn * 64 + lr;
    const int ofsA = rowAl * 64 + (kb ^ ((rowAl >> 1) & 3)) * 16;
    const int ofsB = rowBl * 64 + (kb ^ ((rowBl >> 1) & 3)) * 16;

    f32x4 acc[8][4];
    #pragma unroll
    for (int i = 0; i < 8; ++i)
        #pragma unroll
        for (int j = 0; j < 4; ++j)
            acc[i][j] = (f32x4){0.f, 0.f, 0.f, 0.f};

    STAGE_A(0); STAGE_B(0);
    STAGE_A(1); STAGE_B(1);
    STAGE_A(2); STAGE_B(2);

    for (int t = 0; t < NT; ++t) {
        if (t + 2 < NT)      asm volatile("s_waitcnt vmcnt(8)" ::: "memory");
        else if (t + 1 < NT) asm volatile("s_waitcnt vmcnt(4)" ::: "memory");
        else                 asm volatile("s_waitcnt vmcnt(0)" ::: "memory");
        __builtin_amdgcn_s_barrier();
        __builtin_amdgcn_sched_barrier(0);

        const char* Ab = (const char*)As[t & 3];
        const char* Bb = (const char*)Bs[t & 3];

        short8 bf[4], af[4];
        #pragma unroll
        for (int j = 0; j < 4; ++j)
            bf[j] = *reinterpret_cast<const short8*>(Bb + ofsB + 1024 * j);
        #pragma unroll
        for (int i = 0; i < 4; ++i)
            af[i] = *reinterpret_cast<const short8*>(Ab + ofsA + 1024 * i);
        if (t + 3 < NT) STAGE_A(t + 3);
        __builtin_amdgcn_s_setprio(1);
        #pragma unroll
        for (int i = 0; i < 4; ++i)
            #pragma unroll
            for (int j = 0; j < 4; ++j)
                acc[i][j] = __builtin_amdgcn_mfma_f32_16x16x32_bf16(
                    af[i], bf[j], acc[i][j], 0, 0, 0);
        __builtin_amdgcn_s_setprio(0);

        __builtin_amdgcn_s_barrier();
        __builtin_amdgcn_sched_barrier(0);
        #pragma unroll
        for (int i = 0; i < 4; ++i)
            af[i] = *reinterpret_cast<const short8*>(Ab + ofsA + 1024 * (i + 4));
        if (t + 3 < NT) STAGE_B(t + 3);
        __builtin_amdgcn_s_setprio(1);
        #pragma unroll
        for (int i = 0; i < 4; ++i)
            #pragma unroll
            for (int j = 0; j < 4; ++j)
                acc[i + 4][j] = __builtin_amdgcn_mfma_f32_16x16x32_bf16(
                    af[i], bf[j], acc[i + 4][j], 0, 0, 0);
        __builtin_amdgcn_s_setprio(0);
    }

    const int orow4 = (lane >> 4) * 4;
    #pragma unroll
    for (int i = 0; i < 8; ++i) {
        #pragma unroll
        for (int j = 0; j < 4; ++j) {
            const size_t col = colB0 + wn * 64 + j * 16 + lr;
            const float bb = bias[col];
            float v[4];
            #pragma unroll
            for (int r = 0; r < 4; ++r) v[r] = acc[i][j][r] + bb;
            const size_t row0 = rowA0 + wm * 128 + i * 16 + orow4;
            #pragma unroll
            for (int r = 0; r < 4; ++r)
                Cb[(row0 + r) * N + col] = __float2bfloat16(v[r]);
            if (vt && (int)col >= 2 * C_) {
                const int vc = (int)col - 2 * C_;
                const int hh = vc >> 6, dd = vc & 63;
                const int bb_ = (int)(row0 >> 11);
                const int t0  = (int)(row0 & 2047);
                ushort4 o;
                o.x = f2bf(v[0]); o.y = f2bf(v[1]); o.z = f2bf(v[2]); o.w = f2bf(v[3]);
                *reinterpret_cast<ushort4*>(
                    vt + (((size_t)(bb_ * NH + hh) * 64 + dd) * T_ + t0)) = o;
            }
        }
    }
    #undef STAGE_A
    #undef STAGE_B
}

// ---------------------------------------------------------------------------
// 128x128 bf16 MFMA GEMM (2-phase): output projection (unchanged).
// ---------------------------------------------------------------------------
#define GBM 128
#define GBN 128
#define GBK 64

__global__ __launch_bounds__(256) void gemm_bf16_mfma(
    const __hip_bfloat16* __restrict__ A,
    const __hip_bfloat16* __restrict__ Bt,
    const float* __restrict__ bias,
    float* __restrict__ Cf,
    int M, int N, int K, int gx)
{
    __shared__ __align__(16) __hip_bfloat16 As[GBM * GBK];
    __shared__ __align__(16) __hip_bfloat16 Bs[GBN * GBK];

    const int nwg = (int)gridDim.x;
    const int orig = (int)blockIdx.x;
    const int qq = nwg >> 3, rr = nwg & 7;
    const int xcd = orig & 7, off = orig >> 3;
    const int wgid = (xcd < rr ? xcd * (qq + 1)
                               : rr * (qq + 1) + (xcd - rr) * qq) + off;
    const int bx = wgid % gx;
    const int by = wgid / gx;

    const int tid = threadIdx.x;
    const int lane = tid & 63;
    const int wid = tid >> 6;
    const int wr = wid >> 1, wc = wid & 1;
    const int lr = lane & 15;
    const int lk = (lane >> 4) * 8;

    const size_t rowA0 = (size_t)by * GBM;
    const size_t colB0 = (size_t)bx * GBN;

    f32x4 acc[4][4];
    #pragma unroll
    for (int i = 0; i < 4; ++i)
        #pragma unroll
        for (int j = 0; j < 4; ++j)
            acc[i][j] = (f32x4){0.f, 0.f, 0.f, 0.f};

    for (int k0 = 0; k0 < K; k0 += GBK) {
        #pragma unroll
        for (int it = 0; it < 4; ++it) {
            const int idx = tid + it * 256;
            const int r  = idx >> 3;
            const int kc = (idx & 7) * 8;
            gload_lds16(A  + (rowA0 + r) * K + k0 + kc, &As[idx * 8]);
            gload_lds16(Bt + (colB0 + r) * K + k0 + kc, &Bs[idx * 8]);
        }
        __syncthreads();

        #pragma unroll
        for (int kk = 0; kk < GBK; kk += 32) {
            short8 af[4], bf[4];
            #pragma unroll
            for (int i = 0; i < 4; ++i)
                af[i] = *reinterpret_cast<const short8*>(
                    &As[(wr * 64 + i * 16 + lr) * GBK + kk + lk]);
            #pragma unroll
            for (int j = 0; j < 4; ++j)
                bf[j] = *reinterpret_cast<const short8*>(
                    &Bs[(wc * 64 + j * 16 + lr) * GBK + kk + lk]);
            #pragma unroll
            for (int i = 0; i < 4; ++i)
                #pragma unroll
                for (int j = 0; j < 4; ++j)
                    acc[i][j] = __builtin_amdgcn_mfma_f32_16x16x32_bf16(
                        af[i], bf[j], acc[i][j], 0, 0, 0);
        }
        __syncthreads();
    }

    const int orow = (lane >> 4) * 4;
    #pragma unroll
    for (int i = 0; i < 4; ++i) {
        #pragma unroll
        for (int j = 0; j < 4; ++j) {
            const size_t col = colB0 + wc * 64 + j * 16 + lr;
            const float bb = bias[col];
            #pragma unroll
            for (int r = 0; r < 4; ++r) {
                const size_t row = rowA0 + wr * 64 + i * 16 + orow + r;
                Cf[row * N + col] = acc[i][j][r] + bb;
            }
        }
    }
}

// ---------------------------------------------------------------------------
// MFMA flash attention v4: 32x32x16 shape. Grid (B*NH, T/64), 128 threads =
// 2 waves x 32 q-rows. Double-buffered K/V^T 64x64 tiles (XOR-swizzled).
// Static-max exp2 softmax (scale folded into Q), l via per-lane partials +
// end shuffle-reduce, P through per-wave swizzled LDS. Output bf16 y.
// C/D layout (m74/m101): col=lane&31, row=(reg&3)+8*(reg>>2)+4*(lane>>5).
// A/B frags: row/col=lane&31, k=(lane>>5)*8+j.
// ---------------------------------------------------------------------------
__global__ __launch_bounds__(128) void attn_mfma_kernel(
    const __hip_bfloat16* __restrict__ qkvb,  // [B,T,3C] bf16
    const __hip_bfloat16* __restrict__ vtg,   // [B*NH][64][T] bf16
    __hip_bfloat16* __restrict__ yb)          // [B,T,C] bf16
{
    const int bh = blockIdx.x;
    const int b = bh >> 4, h = bh & 15;
    const int qt = (int)gridDim.y - 1 - (int)blockIdx.y;   // heavy tiles first
    const int tid = threadIdx.x;
    const int w = tid >> 6;            // 0..1
    const int lane = tid & 63;
    const int l31 = lane & 31, g = lane >> 5;

    __shared__ __align__(16) __hip_bfloat16 Ks[2][64 * 64];
    __shared__ __align__(16) __hip_bfloat16 Vts[2][64 * 64];
    __shared__ __align__(16) __hip_bfloat16 Pl[2][32 * 64];

    const int qrow = qt * 64 + w * 32;         // wave's first q row
    const size_t s3C = 3 * C_;

    // Q A-frags (row=l31, k=d=s*16+g*8+j), pre-scaled by 0.125*log2(e)
    const float qscale = 0.125f * 1.44269504f;
    const __hip_bfloat16* qp =
        qkvb + ((size_t)(b * T_) + qrow + l31) * s3C + h * 64 + g * 8;
    short8 qa[4];
    #pragma unroll
    for (int s = 0; s < 4; ++s) {
        qa[s] = *reinterpret_cast<const short8*>(qp + s * 16);
        #pragma unroll
        for (int j = 0; j < 8; ++j) {
            const float f = __uint_as_float(((unsigned)(unsigned short)qa[s][j]) << 16);
            qa[s][j] = (short)f2bf(f * qscale);
        }
    }

    f32x16 o0 = {}, o1 = {};          // O columns d = l31 / 32+l31
    float lp[16];
    #pragma unroll
    for (int i = 0; i < 16; ++i) lp[i] = 0.f;

    char* PlB = (char*)Pl[w];

    auto STAGE = [&](int t, int bi) {
        #pragma unroll
        for (int rr = 0; rr < 4; ++rr) {
            const int slot = rr * 128 + tid;      // 0..511
            const int row = slot >> 3;            // key (K) / dim (Vt)
            const int gblk = (slot & 7) ^ (row & 7);
            gload_lds16(qkvb + ((size_t)(b * T_) + t * 64 + row) * s3C
                             + C_ + h * 64 + gblk * 8,
                        (char*)Ks[bi] + slot * 16);
            gload_lds16(vtg + ((size_t)bh * 64 + row) * T_ + t * 64 + gblk * 8,
                        (char*)Vts[bi] + slot * 16);
        }
    };

    STAGE(0, 0);
    __syncthreads();
    int buf = 0;

    for (int t = 0; t <= qt; ++t) {
        if (t < qt) STAGE(t + 1, buf ^ 1);

        const char* KsB  = (const char*)Ks[buf];
        const char* VtsB = (const char*)Vts[buf];

        // S = Q K^T (log2-scaled): two 32x32 key blocks
        f32x16 s0 = {}, s1 = {};
        __builtin_amdgcn_s_setprio(1);
        #pragma unroll
        for (int s = 0; s < 4; ++s) {
            const int blk = (s * 2 + g) ^ (l31 & 7);
            const short8 kf0 = *reinterpret_cast<const short8*>(
                KsB + l31 * 128 + blk * 16);
            const short8 kf1 = *reinterpret_cast<const short8*>(
                KsB + (32 + l31) * 128 + blk * 16);
            s0 = __builtin_amdgcn_mfma_f32_32x32x16_bf16(qa[s], kf0, s0, 0, 0, 0);
            s1 = __builtin_amdgcn_mfma_f32_32x32x16_bf16(qa[s], kf1, s1, 0, 0, 0);
        }
        __builtin_amdgcn_s_setprio(0);

        // softmax: p = exp2(s); mask only on the diagonal tile
        const bool diag = (t == qt);
        #pragma unroll
        for (int reg = 0; reg < 16; ++reg) {
            const int row = (reg & 3) + 8 * (reg >> 2) + 4 * g;   // q local 0..31
            float v0 = s0[reg], v1 = s1[reg];
            if (diag) {
                const int qg = w * 32 + row;       // q within tile (key base = 0)
                v0 = (l31 <= qg)      ? v0 : -INFINITY;
                v1 = (32 + l31 <= qg) ? v1 : -INFINITY;
            }
            const float p0 = exp2f(v0);
            const float p1 = exp2f(v1);
            lp[reg] += p0 + p1;
            const int a0 = row * 128 + (((l31 >> 3) ^ (row & 7)) * 16) + (l31 & 7) * 2;
            *reinterpret_cast<unsigned short*>(PlB + a0)        = f2bf_fast(p0);
            *reinterpret_cast<unsigned short*>(PlB + (a0 ^ 64)) = f2bf_fast(p1);
        }

        // PV: O += P V (A=P rows q, B=V^T cols d)
        __builtin_amdgcn_s_setprio(1);
        #pragma unroll
        for (int s = 0; s < 4; ++s) {
            const int blk = (s * 2 + g) ^ (l31 & 7);
            const short8 pa = *reinterpret_cast<const short8*>(
                PlB + l31 * 128 + blk * 16);
            const short8 vf0 = *reinterpret_cast<const short8*>(
                VtsB + l31 * 128 + blk * 16);
            const short8 vf1 = *reinterpret_cast<const short8*>(
                VtsB + (32 + l31) * 128 + blk * 16);
            o0 = __builtin_amdgcn_mfma_f32_32x32x16_bf16(pa, vf0, o0, 0, 0, 0);
            o1 = __builtin_amdgcn_mfma_f32_32x32x16_bf16(pa, vf1, o1, 0, 0, 0);
        }
        __builtin_amdgcn_s_setprio(0);

        __syncthreads();   // drains staged loads for t+1; waves re-sync
        buf ^= 1;
    }

    // l: reduce per-lane partials across the 32-lane key group
    #pragma unroll
    for (int reg = 0; reg < 16; ++reg) {
        float v = lp[reg];
        v += __shfl_xor(v, 1);
        v += __shfl_xor(v, 2);
        v += __shfl_xor(v, 4);
        v += __shfl_xor(v, 8);
        v += __shfl_xor(v, 16);
        lp[reg] = 1.f / v;
    }

    // epilogue: y[qg][h*64 + d], d = l31 / 32+l31
    #pragma unroll
    for (int reg = 0; reg < 16; ++reg) {
        const int row = (reg & 3) + 8 * (reg >> 2) + 4 * g;
        const int qg = qrow + row;
        __hip_bfloat16* yp = yb + ((size_t)(b * T_) + qg) * C_ + h * 64;
        *reinterpret_cast<unsigned short*>(yp + l31)      = f2bf_fast(o0[reg] * lp[reg]);
        *reinterpret_cast<unsigned short*>(yp + 32 + l31) = f2bf_fast(o1[reg] * lp[reg]);
    }
}

// ---------------------------------------------------------------------------
extern "C" void kernel_launch(void* const* d_in, const int* in_sizes, int n_in,
                              void* d_out, int out_size, void* d_ws, size_t ws_size,
                              hipStream_t stream)
{
    const float* x     = (const float*)d_in[0];
    // d_in[1] = causal mask (tril), handled analytically
    const float* W_qkv = (const float*)d_in[2];
    const float* b_qkv = (const float*)d_in[3];
    const float* W_out = (const float*)d_in[4];
    const float* b_out = (const float*)d_in[5];
    float* out = (float*)d_out;

    __hip_bfloat16* qkvb = (__hip_bfloat16*)d_ws;                  // [B,T,3C]
    __hip_bfloat16* vtg  = qkvb + (size_t)B_ * T_ * 3 * C_;        // [B*NH][64][T]
    __hip_bfloat16* xb   = vtg  + (size_t)B_ * NH * 64 * T_;       // [B,T,C]
    __hip_bfloat16* wqt  = xb   + (size_t)B_ * T_ * C_;            // [3C, C]
    __hip_bfloat16* wot  = wqt  + (size_t)3 * C_ * C_;             // [C, C]
    __hip_bfloat16* yb   = wot  + (size_t)C_ * C_;                 // [B,T,C]

    const int M = B_ * T_;   // 4096

    cast_bf16_kernel<<<(M * C_ / 4 + 255) / 256, 256, 0, stream>>>(x, xb, M * C_ / 4);
    {
        dim3 g(3 * C_ / 32, C_ / 32);
        transpose_cast_kernel<<<g, 256, 0, stream>>>(W_qkv, wqt, C_, 3 * C_);
    }
    {
        dim3 g(C_ / 32, C_ / 32);
        transpose_cast_kernel<<<g, 256, 0, stream>>>(W_out, wot, C_, C_);
    }

    // 1) QKV projection (256x256 phase-interleaved) -> bf16 qkv + V^T
    {
        const int gx = 3 * C_ / QBN, gy = M / QBM;   // 12 x 16 = 192
        gemm_bf16_8ph<<<dim3(gx * gy), 512, 0, stream>>>(
            xb, wqt, b_qkv, qkvb, vtg, M, 3 * C_, C_, gx);
    }
    // 2) MFMA flash attention (32x32) -> bf16 y
    {
        dim3 grid(B_ * NH, T_ / 64);
        attn_mfma_kernel<<<grid, 128, 0, stream>>>(qkvb, vtg, yb);
    }
    // 3) output projection (128x128) -> fp32 out
    {
        const int gx = C_ / GBN, gy = M / GBM;       // 8 x 32 = 256
        gemm_bf16_mfma<<<dim3(gx * gy), 256, 0, stream>>>(
            yb, wot, b_out, out, M, C_, C_, gx);
    }
}